// Round 2
// baseline (199.719 us; speedup 1.0000x reference)
//
#include <hip/hip_runtime.h>

#define NNODES 50000
#define NEDGES 800000
#define HD 128            // HEADS*OUT_DIM
#define NEG 0.2f
#define SCAN_BLOCKS ((NNODES + 255) / 256)   // 196
#define MTILE 64
#define LDW 136           // bf16 row stride in LDS
#define MAXD 64           // per-node LDS cache cap in gat_node
#define GEMMB ((NNODES + MTILE - 1) / MTILE) // 782
#define EPB 1024          // edges per gemm block (782*1024 >= 800000)

typedef __attribute__((ext_vector_type(8))) short short8;
typedef __attribute__((ext_vector_type(4))) float floatx4;

static __device__ inline unsigned short f2bf(float f) {
    unsigned u = __float_as_uint(f);
    return (unsigned short)((u + 0x7FFF + ((u >> 16) & 1)) >> 16);
}
static __device__ inline float bf2f(unsigned short u) {
    return __uint_as_float(((unsigned)u) << 16);
}
static __device__ inline float lrelu_exp(float a) {
    a = (a > 0.f) ? a : NEG * a;
    return __expf(a);
}

// ---------------------------------------------------------------------------
// Kernel 1: 782 blocks, each = one 64-row GEMM tile AND a 1024-edge degree
// chunk. Edge dst loads issue first (deepest latency), histogram atomics
// issue before the staging barrier so their latency hides under W-staging +
// MFMA. x A-fragments are loaded straight to registers (no xl buffer) =>
// LDS 52->34.8 KB => 4 blocks/CU. Epilogue C-bounce reuses Wl.
// ---------------------------------------------------------------------------
__global__ __launch_bounds__(256, 4) void gat_main(
    const float* __restrict__ x, const float* __restrict__ W,
    const float* __restrict__ att_src, const float* __restrict__ att_dst,
    const int* __restrict__ ei,
    unsigned short* __restrict__ h, float* __restrict__ asrc,
    float* __restrict__ adst, int* __restrict__ deg, int* __restrict__ rank)
{
    __shared__ unsigned short Wl[128 * LDW];          // 34816 B
    const int t = threadIdx.x;
    const int rowBase = blockIdx.x * MTILE;

    // ---- edge chunk: dst loads first (deepest latency, coalesced) ----
    const int eBase = blockIdx.x * EPB;
    int dstv[4];
#pragma unroll
    for (int j = 0; j < 4; j++) {
        int e = eBase + j * 256 + t;
        dstv[j] = (e < NEDGES) ? ei[NEDGES + e] : -1;
    }

    // ---- W stage: fp32 -> bf16 into LDS ----
    for (int idx = t * 8; idx < 128 * 128; idx += 2048) {
        int r = idx >> 7, c = idx & 127;
        float4 v0 = *(const float4*)(W + idx);
        float4 v1 = *(const float4*)(W + idx + 4);
        short8 u;
        u[0] = (short)f2bf(v0.x); u[1] = (short)f2bf(v0.y);
        u[2] = (short)f2bf(v0.z); u[3] = (short)f2bf(v0.w);
        u[4] = (short)f2bf(v1.x); u[5] = (short)f2bf(v1.y);
        u[6] = (short)f2bf(v1.z); u[7] = (short)f2bf(v1.w);
        *(short8*)(Wl + r * LDW + c) = u;
    }

    // ---- x A-fragments: global -> registers (no LDS round trip) ----
    const int wave = t >> 6;
    const int lane = t & 63;
    const int c16  = lane & 15;
    const int quad = lane >> 4;
    const int xr   = rowBase + wave * 16 + c16;
    short8 av[4];
#pragma unroll
    for (int kc = 0; kc < 4; kc++) {
        float4 v0 = make_float4(0.f, 0.f, 0.f, 0.f);
        float4 v1 = v0;
        if (xr < NNODES) {
            const float* p = x + (size_t)xr * 128 + kc * 32 + quad * 8;
            v0 = *(const float4*)p;
            v1 = *(const float4*)(p + 4);
        }
        short8 u;
        u[0] = (short)f2bf(v0.x); u[1] = (short)f2bf(v0.y);
        u[2] = (short)f2bf(v0.z); u[3] = (short)f2bf(v0.w);
        u[4] = (short)f2bf(v1.x); u[5] = (short)f2bf(v1.y);
        u[6] = (short)f2bf(v1.z); u[7] = (short)f2bf(v1.w);
        av[kc] = u;
    }

    // ---- degree histogram: atomics overlap with staging/MFMA latency ----
#pragma unroll
    for (int j = 0; j < 4; j++)
        if (dstv[j] >= 0)
            rank[eBase + j * 256 + t] = atomicAdd(deg + dstv[j], 1);

    __syncthreads();

    floatx4 acc[8];
#pragma unroll
    for (int nt = 0; nt < 8; nt++) acc[nt] = (floatx4)(0.f);

#pragma unroll
    for (int kc = 0; kc < 4; kc++) {
#pragma unroll
        for (int nt = 0; nt < 8; nt++) {
            short8 bv = *(const short8*)(Wl + (nt * 16 + c16) * LDW + kc * 32 + quad * 8);
            acc[nt] = __builtin_amdgcn_mfma_f32_16x16x32_bf16(av[kc], bv, acc[nt], 0, 0, 0);
        }
    }

    float As[8], Ad[8];
#pragma unroll
    for (int nt = 0; nt < 8; nt++) {
        As[nt] = att_src[nt * 16 + c16];
        Ad[nt] = att_dst[nt * 16 + c16];
    }
#pragma unroll
    for (int r = 0; r < 4; r++) {
        const int gr = rowBase + wave * 16 + quad * 4 + r;
#pragma unroll
        for (int hh = 0; hh < 4; hh++) {
            float ps = acc[2 * hh][r] * As[2 * hh] + acc[2 * hh + 1][r] * As[2 * hh + 1];
            float pd = acc[2 * hh][r] * Ad[2 * hh] + acc[2 * hh + 1][r] * Ad[2 * hh + 1];
#pragma unroll
            for (int m = 8; m >= 1; m >>= 1) {
                ps += __shfl_xor(ps, m, 64);
                pd += __shfl_xor(pd, m, 64);
            }
            if (c16 == 0 && gr < NNODES) {
                asrc[gr * 4 + hh] = ps;
                adst[gr * 4 + hh] = pd;
            }
        }
    }

    // ---- epilogue: C bounce through Wl (W is dead now) for 16B stores ----
    __syncthreads();
#pragma unroll
    for (int r = 0; r < 4; r++) {
        const int lr = wave * 16 + quad * 4 + r;
#pragma unroll
        for (int nt = 0; nt < 8; nt++)
            Wl[lr * LDW + nt * 16 + c16] = f2bf(acc[nt][r]);
    }
    __syncthreads();
    for (int idx = t * 8; idx < MTILE * 128; idx += 2048) {
        int r = idx >> 7, c = idx & 127;
        int g = rowBase + r;
        if (g < NNODES)
            *(short8*)(h + (size_t)g * HD + c) = *(const short8*)(Wl + r * LDW + c);
    }
}

// ---------------------------------------------------------------------------
// Kernel 2: block-level exclusive scan of deg -> coffp, block sums scanned
// in-place by the LAST block to finish (threadfence + atomic ticket).
// Consumers reconstruct coff[i] = coffp[i] + bsum[i>>8].
// ---------------------------------------------------------------------------
__global__ __launch_bounds__(256) void gat_scan(
    const int* __restrict__ deg, int* __restrict__ coffp,
    int* __restrict__ bsum, int* __restrict__ cnt)
{
    __shared__ int sh[256];
    __shared__ int isLast;
    const int t = threadIdx.x;
    const int i = blockIdx.x * 256 + t;
    int v = (i < NNODES) ? deg[i] : 0;
    sh[t] = v;
    __syncthreads();
    for (int off = 1; off < 256; off <<= 1) {
        int u = (t >= off) ? sh[t - off] : 0;
        __syncthreads();
        sh[t] += u;
        __syncthreads();
    }
    if (i < NNODES) coffp[i] = sh[t] - v;
    if (t == 255) {
        bsum[blockIdx.x] = sh[255];
        __threadfence();                       // publish before ticket
        int c = atomicAdd(cnt, 1);
        isLast = (c == SCAN_BLOCKS - 1);
    }
    __syncthreads();
    if (!isLast) return;

    __threadfence();                           // acquire all blocks' bsum
    int bv = (t < SCAN_BLOCKS) ? bsum[t] : 0;
    sh[t] = bv;
    __syncthreads();
    for (int off = 1; off < 256; off <<= 1) {
        int u = (t >= off) ? sh[t - off] : 0;
        __syncthreads();
        sh[t] += u;
        __syncthreads();
    }
    if (t < SCAN_BLOCKS) bsum[t] = sh[t] - bv;
}

// ---------------------------------------------------------------------------
// Kernel 3: CSR fill — scatter int2{src, edge_id} in one 8B store.
// ---------------------------------------------------------------------------
__global__ __launch_bounds__(256) void gat_fill(
    const int* __restrict__ ei, const int* __restrict__ rank,
    const int* __restrict__ coffp, const int* __restrict__ bsum,
    int2* __restrict__ csr_se)
{
    int e = blockIdx.x * 256 + threadIdx.x;
    int s = ei[e], d = ei[NEDGES + e];
    int slot = coffp[d] + bsum[d >> 8] + rank[e];
    csr_se[slot] = make_int2(s, e);
}

// ---------------------------------------------------------------------------
// Kernel 4: per-node. Phase 1: gather asrc[src] (L2-resident), compute exp
// weights, sum per head, stash (src,eid,w4) in LDS. Phase 2: normalize +
// gather h rows 4-way unrolled; write apool[eid] from the stash.
// 32 lanes/node, 8 nodes/block.
// ---------------------------------------------------------------------------
__global__ __launch_bounds__(256) void gat_node(
    const int* __restrict__ coffp, const int* __restrict__ bsum,
    const int2* __restrict__ csr_se, const float* __restrict__ asrc,
    const float* __restrict__ adst, const unsigned short* __restrict__ h,
    const float* __restrict__ bias, float* __restrict__ out,
    float* __restrict__ apool)
{
    __shared__ int   sh_src[8 * MAXD];
    __shared__ int   sh_eid[8 * MAXD];
    __shared__ float sh_w[8 * MAXD * 4];
    int t = threadIdx.x;
    int node8 = t >> 5;
    int n = blockIdx.x * 8 + node8;
    int k = t & 31;
    int head = k >> 3;
    int beg = coffp[n] + bsum[n >> 8];
    int end = (n + 1 < NNODES) ? (coffp[n + 1] + bsum[(n + 1) >> 8]) : NEDGES;
    const float4 bn = *(const float4*)(adst + n * 4);   // per-node broadcast

    // phase 1: weight compute + sums + LDS stash
    float4 sum = make_float4(0.f, 0.f, 0.f, 0.f);
    for (int j = beg + k; j < end; j += 32) {
        int2 se = csr_se[j];
        float4 a = *(const float4*)(asrc + se.x * 4);
        float4 wv;
        wv.x = lrelu_exp(a.x + bn.x);
        wv.y = lrelu_exp(a.y + bn.y);
        wv.z = lrelu_exp(a.z + bn.z);
        wv.w = lrelu_exp(a.w + bn.w);
        sum.x += wv.x; sum.y += wv.y; sum.z += wv.z; sum.w += wv.w;
        int i = j - beg;
        if (i < MAXD) {
            sh_src[node8 * MAXD + i] = se.x;
            sh_eid[node8 * MAXD + i] = se.y;
            *(float4*)(sh_w + (node8 * MAXD + i) * 4) = wv;
        }
    }
#pragma unroll
    for (int m = 16; m >= 1; m >>= 1) {
        sum.x += __shfl_xor(sum.x, m, 64);
        sum.y += __shfl_xor(sum.y, m, 64);
        sum.z += __shfl_xor(sum.z, m, 64);
        sum.w += __shfl_xor(sum.w, m, 64);
    }
    float rs[4];
    rs[0] = 1.f / (sum.x + 1e-16f);
    rs[1] = 1.f / (sum.y + 1e-16f);
    rs[2] = 1.f / (sum.z + 1e-16f);
    rs[3] = 1.f / (sum.w + 1e-16f);
    const float rsel = rs[head];
    __syncthreads();

    // phase 2: gather h rows; src/w from LDS -> no global dependency chain
    const int cnt = end - beg;
    const int lim = (cnt < MAXD) ? cnt : MAXD;
    const int base = node8 * MAXD;
    float4 acc = *(const float4*)(bias + k * 4);
    float4 acc2 = make_float4(0.f, 0.f, 0.f, 0.f);
    int i = 0;
    for (; i + 4 <= lim; i += 4) {
        int s0 = sh_src[base + i];
        int s1 = sh_src[base + i + 1];
        int s2 = sh_src[base + i + 2];
        int s3 = sh_src[base + i + 3];
        float w0 = sh_w[(base + i) * 4 + head] * rsel;
        float w1 = sh_w[(base + i + 1) * 4 + head] * rsel;
        float w2 = sh_w[(base + i + 2) * 4 + head] * rsel;
        float w3 = sh_w[(base + i + 3) * 4 + head] * rsel;
        ushort4 u0 = *(const ushort4*)(h + (size_t)s0 * HD + k * 4);
        ushort4 u1 = *(const ushort4*)(h + (size_t)s1 * HD + k * 4);
        ushort4 u2 = *(const ushort4*)(h + (size_t)s2 * HD + k * 4);
        ushort4 u3 = *(const ushort4*)(h + (size_t)s3 * HD + k * 4);
        acc.x  = fmaf(bf2f(u0.x), w0, acc.x);
        acc.y  = fmaf(bf2f(u0.y), w0, acc.y);
        acc.z  = fmaf(bf2f(u0.z), w0, acc.z);
        acc.w  = fmaf(bf2f(u0.w), w0, acc.w);
        acc2.x = fmaf(bf2f(u1.x), w1, acc2.x);
        acc2.y = fmaf(bf2f(u1.y), w1, acc2.y);
        acc2.z = fmaf(bf2f(u1.z), w1, acc2.z);
        acc2.w = fmaf(bf2f(u1.w), w1, acc2.w);
        acc.x  = fmaf(bf2f(u2.x), w2, acc.x);
        acc.y  = fmaf(bf2f(u2.y), w2, acc.y);
        acc.z  = fmaf(bf2f(u2.z), w2, acc.z);
        acc.w  = fmaf(bf2f(u2.w), w2, acc.w);
        acc2.x = fmaf(bf2f(u3.x), w3, acc2.x);
        acc2.y = fmaf(bf2f(u3.y), w3, acc2.y);
        acc2.z = fmaf(bf2f(u3.z), w3, acc2.z);
        acc2.w = fmaf(bf2f(u3.w), w3, acc2.w);
    }
    for (; i < lim; i++) {
        int s0 = sh_src[base + i];
        float w0 = sh_w[(base + i) * 4 + head] * rsel;
        ushort4 u0 = *(const ushort4*)(h + (size_t)s0 * HD + k * 4);
        acc.x = fmaf(bf2f(u0.x), w0, acc.x);
        acc.y = fmaf(bf2f(u0.y), w0, acc.y);
        acc.z = fmaf(bf2f(u0.z), w0, acc.z);
        acc.w = fmaf(bf2f(u0.w), w0, acc.w);
    }
    for (int j = beg + MAXD; j < end; j++) {        // rare overflow fallback
        int2 se = csr_se[j];
        float4 a = *(const float4*)(asrc + se.x * 4);
        float w4[4];
        w4[0] = lrelu_exp(a.x + bn.x);
        w4[1] = lrelu_exp(a.y + bn.y);
        w4[2] = lrelu_exp(a.z + bn.z);
        w4[3] = lrelu_exp(a.w + bn.w);
        float w0 = w4[head] * rsel;
        ushort4 u0 = *(const ushort4*)(h + (size_t)se.x * HD + k * 4);
        acc.x = fmaf(bf2f(u0.x), w0, acc.x);
        acc.y = fmaf(bf2f(u0.y), w0, acc.y);
        acc.z = fmaf(bf2f(u0.z), w0, acc.z);
        acc.w = fmaf(bf2f(u0.w), w0, acc.w);
        if (k == 0)
            apool[se.y] = 0.25f * (w4[0] * rs[0] + w4[1] * rs[1] +
                                   w4[2] * rs[2] + w4[3] * rs[3]);
    }
    acc.x += acc2.x; acc.y += acc2.y; acc.z += acc2.z; acc.w += acc2.w;
    *(float4*)(out + (size_t)n * HD + k * 4) = acc;

    // alpha_pooled from the LDS stash
    for (int i2 = k; i2 < lim; i2 += 32) {
        float4 w = *(const float4*)(sh_w + (base + i2) * 4);
        apool[sh_eid[base + i2]] =
            0.25f * (w.x * rs[0] + w.y * rs[1] + w.z * rs[2] + w.w * rs[3]);
    }
}

// ---------------------------------------------------------------------------
extern "C" void kernel_launch(void* const* d_in, const int* in_sizes, int n_in,
                              void* d_out, int out_size, void* d_ws, size_t ws_size,
                              hipStream_t stream)
{
    const float* x       = (const float*)d_in[0];
    const int*   ei      = (const int*)d_in[1];
    const float* W       = (const float*)d_in[2];
    const float* att_src = (const float*)d_in[3];
    const float* att_dst = (const float*)d_in[4];
    const float* bias    = (const float*)d_in[5];

    float* out   = (float*)d_out;                    // (N,128)
    float* apool = out + (size_t)NNODES * HD;        // (E,)

    // workspace layout (aligned chunks)
    unsigned short* h = (unsigned short*)d_ws;            // N*128 bf16
    float* asrc   = (float*)(h + (size_t)NNODES * HD);    // N*4
    float* adst   = asrc + NNODES * 4;               // N*4
    int*   deg    = (int*)(adst + NNODES * 4);       // N
    int*   cnt    = deg + NNODES;                    // 1 (+1 pad)
    int*   coffp  = cnt + 2;                         // N (+pad)
    int*   bsum   = coffp + NNODES + 2;              // SCAN_BLOCKS
    int*   rank   = bsum + SCAN_BLOCKS;              // E
    int2*  csr_se = (int2*)(rank + NEDGES);          // E (8B-aligned)

    hipMemsetAsync(deg, 0, (size_t)(NNODES + 2) * sizeof(int), stream);

    gat_main<<<GEMMB, 256, 0, stream>>>(
        x, W, att_src, att_dst, ei, h, asrc, adst, deg, rank);
    gat_scan<<<SCAN_BLOCKS, 256, 0, stream>>>(deg, coffp, bsum, cnt);
    gat_fill<<<NEDGES / 256, 256, 0, stream>>>(ei, rank, coffp, bsum, csr_se);
    gat_node<<<NNODES / 8, 256, 0, stream>>>(
        coffp, bsum, csr_se, asrc, adst, h, bias, out, apool);
}

// Round 3
// 157.641 us; speedup vs baseline: 1.2669x; 1.2669x over previous
//
#include <hip/hip_runtime.h>

#define NNODES 50000
#define NEDGES 800000
#define HD 128            // HEADS*OUT_DIM
#define NEG 0.2f
#define MTILE 64
#define LDW 136           // bf16 row stride in LDS
#define MAXD 64           // per-node LDS cache cap in gat_node
#define GEMMB ((NNODES + MTILE - 1) / MTILE) // 782
#define NBINS 196         // ceil(NNODES/256) coarse bins (dst>>8)
#define CAP 5120          // per-bin capacity (mean 4096, sigma 64 -> +16 sigma)
#define GST 16            // gcnt line-padding stride (1 counter / 64B line)
#define ABLK ((NEDGES + 2047) / 2048)        // 391 bucket blocks, 2048 edges each

typedef __attribute__((ext_vector_type(8))) short short8;
typedef __attribute__((ext_vector_type(4))) float floatx4;

static __device__ inline unsigned short f2bf(float f) {
    unsigned u = __float_as_uint(f);
    return (unsigned short)((u + 0x7FFF + ((u >> 16) & 1)) >> 16);
}
static __device__ inline float bf2f(unsigned short u) {
    return __uint_as_float(((unsigned)u) << 16);
}
static __device__ inline float lrelu_exp(float a) {
    a = (a > 0.f) ? a : NEG * a;
    return __expf(a);
}

// ---------------------------------------------------------------------------
// Kernel 1: blocks [0,GEMMB) = 64-row GEMM tile (bf16 MFMA, fused asrc/adst).
// Blocks [GEMMB, GEMMB+ABLK) = coarse edge bucketing: LDS-private 256-bin
// histogram over dst>>8, ONE global atomic per (block,bin) window reservation
// (77K atomics vs 800K scattered RMWs), scatter (fine|src, eid) to bin window.
// ---------------------------------------------------------------------------
__global__ __launch_bounds__(256, 4) void gat_main(
    const float* __restrict__ x, const float* __restrict__ W,
    const float* __restrict__ att_src, const float* __restrict__ att_dst,
    const int* __restrict__ ei,
    unsigned short* __restrict__ h, float* __restrict__ asrc,
    float* __restrict__ adst, int* __restrict__ gcnt, int2* __restrict__ cbuf)
{
    __shared__ unsigned short Wl[128 * LDW];          // 34816 B
    const int t = threadIdx.x;

    if (blockIdx.x >= GEMMB) {      // ---- coarse bucketing path ----
        int* hist = (int*)Wl;       // [256] reuse gemm LDS
        int* boff = hist + 256;     // [256]
        const int e0 = (blockIdx.x - GEMMB) * 2048 + t * 8;
        const bool act = (e0 < NEDGES);     // tail block: exactly 160 threads
        int4 s0 = make_int4(0, 0, 0, 0), s1 = s0, d0 = s0, d1 = s0;
        if (act) {
            s0 = *(const int4*)(ei + e0);
            s1 = *(const int4*)(ei + e0 + 4);
            d0 = *(const int4*)(ei + NEDGES + e0);
            d1 = *(const int4*)(ei + NEDGES + e0 + 4);
        }
        hist[t] = 0;
        __syncthreads();
        if (act) {
            atomicAdd(&hist[d0.x >> 8], 1); atomicAdd(&hist[d0.y >> 8], 1);
            atomicAdd(&hist[d0.z >> 8], 1); atomicAdd(&hist[d0.w >> 8], 1);
            atomicAdd(&hist[d1.x >> 8], 1); atomicAdd(&hist[d1.y >> 8], 1);
            atomicAdd(&hist[d1.z >> 8], 1); atomicAdd(&hist[d1.w >> 8], 1);
        }
        __syncthreads();
        if (t < NBINS && hist[t] > 0)
            boff[t] = atomicAdd(&gcnt[t * GST], hist[t]);
        __syncthreads();
        if (act) {
            int ss[8] = {s0.x, s0.y, s0.z, s0.w, s1.x, s1.y, s1.z, s1.w};
            int dd[8] = {d0.x, d0.y, d0.z, d0.w, d1.x, d1.y, d1.z, d1.w};
#pragma unroll
            for (int j = 0; j < 8; j++) {
                int b = dd[j] >> 8;
                int slot = atomicAdd(&boff[b], 1);      // LDS atomic
                cbuf[(size_t)b * CAP + slot] =
                    make_int2(((dd[j] & 255) << 16) | ss[j], e0 + j);
            }
        }
        return;
    }

    // ---- GEMM path ----
    const int rowBase = blockIdx.x * MTILE;

    // W stage: fp32 -> bf16 into LDS
    for (int idx = t * 8; idx < 128 * 128; idx += 2048) {
        int r = idx >> 7, c = idx & 127;
        float4 v0 = *(const float4*)(W + idx);
        float4 v1 = *(const float4*)(W + idx + 4);
        short8 u;
        u[0] = (short)f2bf(v0.x); u[1] = (short)f2bf(v0.y);
        u[2] = (short)f2bf(v0.z); u[3] = (short)f2bf(v0.w);
        u[4] = (short)f2bf(v1.x); u[5] = (short)f2bf(v1.y);
        u[6] = (short)f2bf(v1.z); u[7] = (short)f2bf(v1.w);
        *(short8*)(Wl + r * LDW + c) = u;
    }

    // x A-fragments: global -> registers
    const int wave = t >> 6;
    const int lane = t & 63;
    const int c16  = lane & 15;
    const int quad = lane >> 4;
    const int xr   = rowBase + wave * 16 + c16;
    short8 av[4];
#pragma unroll
    for (int kc = 0; kc < 4; kc++) {
        float4 v0 = make_float4(0.f, 0.f, 0.f, 0.f);
        float4 v1 = v0;
        if (xr < NNODES) {
            const float* p = x + (size_t)xr * 128 + kc * 32 + quad * 8;
            v0 = *(const float4*)p;
            v1 = *(const float4*)(p + 4);
        }
        short8 u;
        u[0] = (short)f2bf(v0.x); u[1] = (short)f2bf(v0.y);
        u[2] = (short)f2bf(v0.z); u[3] = (short)f2bf(v0.w);
        u[4] = (short)f2bf(v1.x); u[5] = (short)f2bf(v1.y);
        u[6] = (short)f2bf(v1.z); u[7] = (short)f2bf(v1.w);
        av[kc] = u;
    }
    __syncthreads();

    floatx4 acc[8];
#pragma unroll
    for (int nt = 0; nt < 8; nt++) acc[nt] = (floatx4)(0.f);

#pragma unroll
    for (int kc = 0; kc < 4; kc++) {
#pragma unroll
        for (int nt = 0; nt < 8; nt++) {
            short8 bv = *(const short8*)(Wl + (nt * 16 + c16) * LDW + kc * 32 + quad * 8);
            acc[nt] = __builtin_amdgcn_mfma_f32_16x16x32_bf16(av[kc], bv, acc[nt], 0, 0, 0);
        }
    }

    float As[8], Ad[8];
#pragma unroll
    for (int nt = 0; nt < 8; nt++) {
        As[nt] = att_src[nt * 16 + c16];
        Ad[nt] = att_dst[nt * 16 + c16];
    }
#pragma unroll
    for (int r = 0; r < 4; r++) {
        const int gr = rowBase + wave * 16 + quad * 4 + r;
#pragma unroll
        for (int hh = 0; hh < 4; hh++) {
            float ps = acc[2 * hh][r] * As[2 * hh] + acc[2 * hh + 1][r] * As[2 * hh + 1];
            float pd = acc[2 * hh][r] * Ad[2 * hh] + acc[2 * hh + 1][r] * Ad[2 * hh + 1];
#pragma unroll
            for (int m = 8; m >= 1; m >>= 1) {
                ps += __shfl_xor(ps, m, 64);
                pd += __shfl_xor(pd, m, 64);
            }
            if (c16 == 0 && gr < NNODES) {
                asrc[gr * 4 + hh] = ps;
                adst[gr * 4 + hh] = pd;
            }
        }
    }

    // epilogue: C bounce through Wl for 16B coalesced h stores
    __syncthreads();
#pragma unroll
    for (int r = 0; r < 4; r++) {
        const int lr = wave * 16 + quad * 4 + r;
#pragma unroll
        for (int nt = 0; nt < 8; nt++)
            Wl[lr * LDW + nt * 16 + c16] = f2bf(acc[nt][r]);
    }
    __syncthreads();
    for (int idx = t * 8; idx < MTILE * 128; idx += 2048) {
        int r = idx >> 7, c = idx & 127;
        int g = rowBase + r;
        if (g < NNODES)
            *(short8*)(h + (size_t)g * HD + c) = *(const short8*)(Wl + r * LDW + c);
    }
}

// ---------------------------------------------------------------------------
// Kernel 2: per coarse bin (256 nodes, ~4K edges): fine 256-bin LDS histogram
// + LDS scan -> exact coff[] and final grouped CSR. Zero global atomics.
// Replaces the old deg/scan/fill chain.
// ---------------------------------------------------------------------------
__global__ __launch_bounds__(1024) void gat_bin(
    const int* __restrict__ gcnt, const int2* __restrict__ cbuf,
    int* __restrict__ coff, int2* __restrict__ csr)
{
    __shared__ int sh[256];
    __shared__ int hist[256];
    const int t = threadIdx.x;
    const int b = blockIdx.x;
    const int c_b = gcnt[b * GST];

    // exclusive scan of coarse bin totals -> this bin's base in the CSR
    int v = 0;
    if (t < 256) {
        v = (t < NBINS) ? gcnt[t * GST] : 0;
        sh[t] = v;
        hist[t] = 0;
    }
    __syncthreads();
    for (int off = 1; off < 256; off <<= 1) {
        int u = (t < 256 && t >= off) ? sh[t - off] : 0;
        __syncthreads();
        if (t < 256) sh[t] += u;
        __syncthreads();
    }
    const int binbase = sh[b] - c_b;

    // fine histogram over dst&255
    for (int i = t; i < c_b; i += 1024)
        atomicAdd(&hist[(cbuf[(size_t)b * CAP + i].x >> 16) & 255], 1);
    __syncthreads();

    // scan fine hist -> exclusive offsets; emit coff; hist becomes running off
    int hv = 0;
    if (t < 256) { hv = hist[t]; sh[t] = hv; }
    __syncthreads();
    for (int off = 1; off < 256; off <<= 1) {
        int u = (t < 256 && t >= off) ? sh[t - off] : 0;
        __syncthreads();
        if (t < 256) sh[t] += u;
        __syncthreads();
    }
    if (t < 256) {
        int ex = sh[t] - hv;
        int n = b * 256 + t;
        if (n < NNODES) coff[n] = binbase + ex;
        hist[t] = ex;
    }
    if (b == 0 && t == 0) coff[NNODES] = NEDGES;
    __syncthreads();

    // scatter into final CSR, grouped by dst
    for (int i = t; i < c_b; i += 1024) {
        int2 ew = cbuf[(size_t)b * CAP + i];
        int fine = (ew.x >> 16) & 255;
        int slot = atomicAdd(&hist[fine], 1);           // LDS atomic
        csr[binbase + slot] = make_int2(ew.x & 0xffff, ew.y);
    }
}

// ---------------------------------------------------------------------------
// Kernel 3: per-node. Phase 1: gather asrc[src] (L2-resident), compute exp
// weights, sum per head, stash (src,eid,w4) in LDS. Phase 2: normalize +
// gather h rows 4-way unrolled; write apool[eid] from the stash.
// 32 lanes/node, 8 nodes/block.
// ---------------------------------------------------------------------------
__global__ __launch_bounds__(256) void gat_node(
    const int* __restrict__ coff, const int2* __restrict__ csr_se,
    const float* __restrict__ asrc, const float* __restrict__ adst,
    const unsigned short* __restrict__ h, const float* __restrict__ bias,
    float* __restrict__ out, float* __restrict__ apool)
{
    __shared__ int   sh_src[8 * MAXD];
    __shared__ int   sh_eid[8 * MAXD];
    __shared__ float sh_w[8 * MAXD * 4];
    int t = threadIdx.x;
    int node8 = t >> 5;
    int n = blockIdx.x * 8 + node8;
    int k = t & 31;
    int head = k >> 3;
    int beg = coff[n], end = coff[n + 1];
    const float4 bn = *(const float4*)(adst + n * 4);   // per-node broadcast

    // phase 1: weight compute + sums + LDS stash
    float4 sum = make_float4(0.f, 0.f, 0.f, 0.f);
    for (int j = beg + k; j < end; j += 32) {
        int2 se = csr_se[j];
        float4 a = *(const float4*)(asrc + se.x * 4);
        float4 wv;
        wv.x = lrelu_exp(a.x + bn.x);
        wv.y = lrelu_exp(a.y + bn.y);
        wv.z = lrelu_exp(a.z + bn.z);
        wv.w = lrelu_exp(a.w + bn.w);
        sum.x += wv.x; sum.y += wv.y; sum.z += wv.z; sum.w += wv.w;
        int i = j - beg;
        if (i < MAXD) {
            sh_src[node8 * MAXD + i] = se.x;
            sh_eid[node8 * MAXD + i] = se.y;
            *(float4*)(sh_w + (node8 * MAXD + i) * 4) = wv;
        }
    }
#pragma unroll
    for (int m = 16; m >= 1; m >>= 1) {
        sum.x += __shfl_xor(sum.x, m, 64);
        sum.y += __shfl_xor(sum.y, m, 64);
        sum.z += __shfl_xor(sum.z, m, 64);
        sum.w += __shfl_xor(sum.w, m, 64);
    }
    float rs[4];
    rs[0] = 1.f / (sum.x + 1e-16f);
    rs[1] = 1.f / (sum.y + 1e-16f);
    rs[2] = 1.f / (sum.z + 1e-16f);
    rs[3] = 1.f / (sum.w + 1e-16f);
    const float rsel = rs[head];
    __syncthreads();

    // phase 2: gather h rows; src/w from LDS -> no global dependency chain
    const int cnt = end - beg;
    const int lim = (cnt < MAXD) ? cnt : MAXD;
    const int base = node8 * MAXD;
    float4 acc = *(const float4*)(bias + k * 4);
    float4 acc2 = make_float4(0.f, 0.f, 0.f, 0.f);
    int i = 0;
    for (; i + 4 <= lim; i += 4) {
        int s0 = sh_src[base + i];
        int s1 = sh_src[base + i + 1];
        int s2 = sh_src[base + i + 2];
        int s3 = sh_src[base + i + 3];
        float w0 = sh_w[(base + i) * 4 + head] * rsel;
        float w1 = sh_w[(base + i + 1) * 4 + head] * rsel;
        float w2 = sh_w[(base + i + 2) * 4 + head] * rsel;
        float w3 = sh_w[(base + i + 3) * 4 + head] * rsel;
        ushort4 u0 = *(const ushort4*)(h + (size_t)s0 * HD + k * 4);
        ushort4 u1 = *(const ushort4*)(h + (size_t)s1 * HD + k * 4);
        ushort4 u2 = *(const ushort4*)(h + (size_t)s2 * HD + k * 4);
        ushort4 u3 = *(const ushort4*)(h + (size_t)s3 * HD + k * 4);
        acc.x  = fmaf(bf2f(u0.x), w0, acc.x);
        acc.y  = fmaf(bf2f(u0.y), w0, acc.y);
        acc.z  = fmaf(bf2f(u0.z), w0, acc.z);
        acc.w  = fmaf(bf2f(u0.w), w0, acc.w);
        acc2.x = fmaf(bf2f(u1.x), w1, acc2.x);
        acc2.y = fmaf(bf2f(u1.y), w1, acc2.y);
        acc2.z = fmaf(bf2f(u1.z), w1, acc2.z);
        acc2.w = fmaf(bf2f(u1.w), w1, acc2.w);
        acc.x  = fmaf(bf2f(u2.x), w2, acc.x);
        acc.y  = fmaf(bf2f(u2.y), w2, acc.y);
        acc.z  = fmaf(bf2f(u2.z), w2, acc.z);
        acc.w  = fmaf(bf2f(u2.w), w2, acc.w);
        acc2.x = fmaf(bf2f(u3.x), w3, acc2.x);
        acc2.y = fmaf(bf2f(u3.y), w3, acc2.y);
        acc2.z = fmaf(bf2f(u3.z), w3, acc2.z);
        acc2.w = fmaf(bf2f(u3.w), w3, acc2.w);
    }
    for (; i < lim; i++) {
        int s0 = sh_src[base + i];
        float w0 = sh_w[(base + i) * 4 + head] * rsel;
        ushort4 u0 = *(const ushort4*)(h + (size_t)s0 * HD + k * 4);
        acc.x = fmaf(bf2f(u0.x), w0, acc.x);
        acc.y = fmaf(bf2f(u0.y), w0, acc.y);
        acc.z = fmaf(bf2f(u0.z), w0, acc.z);
        acc.w = fmaf(bf2f(u0.w), w0, acc.w);
    }
    for (int j = beg + MAXD; j < end; j++) {        // rare overflow fallback
        int2 se = csr_se[j];
        float4 a = *(const float4*)(asrc + se.x * 4);
        float w4[4];
        w4[0] = lrelu_exp(a.x + bn.x);
        w4[1] = lrelu_exp(a.y + bn.y);
        w4[2] = lrelu_exp(a.z + bn.z);
        w4[3] = lrelu_exp(a.w + bn.w);
        float w0 = w4[head] * rsel;
        ushort4 u0 = *(const ushort4*)(h + (size_t)se.x * HD + k * 4);
        acc.x = fmaf(bf2f(u0.x), w0, acc.x);
        acc.y = fmaf(bf2f(u0.y), w0, acc.y);
        acc.z = fmaf(bf2f(u0.z), w0, acc.z);
        acc.w = fmaf(bf2f(u0.w), w0, acc.w);
        if (k == 0)
            apool[se.y] = 0.25f * (w4[0] * rs[0] + w4[1] * rs[1] +
                                   w4[2] * rs[2] + w4[3] * rs[3]);
    }
    acc.x += acc2.x; acc.y += acc2.y; acc.z += acc2.z; acc.w += acc2.w;
    *(float4*)(out + (size_t)n * HD + k * 4) = acc;

    // alpha_pooled from the LDS stash
    for (int i2 = k; i2 < lim; i2 += 32) {
        float4 w = *(const float4*)(sh_w + (base + i2) * 4);
        apool[sh_eid[base + i2]] =
            0.25f * (w.x * rs[0] + w.y * rs[1] + w.z * rs[2] + w.w * rs[3]);
    }
}

// ---------------------------------------------------------------------------
extern "C" void kernel_launch(void* const* d_in, const int* in_sizes, int n_in,
                              void* d_out, int out_size, void* d_ws, size_t ws_size,
                              hipStream_t stream)
{
    const float* x       = (const float*)d_in[0];
    const int*   ei      = (const int*)d_in[1];
    const float* W       = (const float*)d_in[2];
    const float* att_src = (const float*)d_in[3];
    const float* att_dst = (const float*)d_in[4];
    const float* bias    = (const float*)d_in[5];

    float* out   = (float*)d_out;                    // (N,128)
    float* apool = out + (size_t)NNODES * HD;        // (E,)

    // workspace layout
    unsigned short* h = (unsigned short*)d_ws;            // N*128 bf16
    float* asrc = (float*)(h + (size_t)NNODES * HD);      // N*4
    float* adst = asrc + NNODES * 4;                      // N*4
    int*   gcnt = (int*)(adst + NNODES * 4);              // NBINS*GST (line-padded)
    int*   coff = gcnt + NBINS * GST;                     // N+1 (+pad)
    int2*  cbuf = (int2*)(coff + NNODES + 4);             // NBINS*CAP
    int2*  csr  = cbuf + (size_t)NBINS * CAP;             // E

    hipMemsetAsync(gcnt, 0, (size_t)NBINS * GST * sizeof(int), stream);

    gat_main<<<GEMMB + ABLK, 256, 0, stream>>>(
        x, W, att_src, att_dst, ei, h, asrc, adst, gcnt, cbuf);
    gat_bin<<<NBINS, 1024, 0, stream>>>(gcnt, cbuf, coff, csr);
    gat_node<<<NNODES / 8, 256, 0, stream>>>(
        coff, csr, asrc, adst, h, bias, out, apool);
}